// Round 5
// baseline (78.096 us; speedup 1.0000x reference)
//
#include <hip/hip_runtime.h>

// FastGaussianModel: values[m] = sum_n exp(-0.5 * sum_d (p[m,d]-q[n,d])^2 * iv[n,d]) * w[n]
// quad' = c' + a.p + b.p^2 per gaussian, K = -0.5*log2(e) folded into coeffs.
//
// Round 5: amortize the coefficient feed. R4 analysis: 64 B coef record per
// ~30 VALU cyc of compute -> feed-bound regardless of scalar vs L1 path.
// Now each thread owns 8 POINTS: one record feeds 56 pk_fma + 16 v_exp
// (~240 cyc) -> fetch latency hides under compute. Occupancy restored by
// slicing gaussians 32 ways (16 pairs = 1 KB per wave-sweep):
// grid = 98 point-tiles x 8 slice-groups, 4 waves/block = 3136 waves ~3/SIMD.
// Fan-in: 4-way LDS reduce per block + 8 atomicAdds/point into memset'd out.

typedef float v2f __attribute__((ext_vector_type(2)));

constexpr int BLOCK           = 256;  // 4 waves
constexpr int WAVES_PER_BLOCK = 4;
constexpr int PTS_PER_LANE    = 8;
constexpr int TILE_PTS        = 64 * PTS_PER_LANE;  // 512 points per block
constexpr int SLICE_GROUPS    = 8;                  // grid.y
constexpr int TOTAL_SLICES    = SLICE_GROUPS * WAVES_PER_BLOCK;  // 32

// --- prep: per-PAIR packed coefficients: 16 floats per gaussian pair ---
// layout per pair i: [a0.xy, a1.xy, a2.xy, b0.xy, b1.xy, b2.xy, c.xy, w.xy]
__global__ void fgm_prep(const float* __restrict__ positions,
                         const float* __restrict__ log_scales,
                         const float* __restrict__ intensities,
                         float* __restrict__ coef, int N, int NpairsPad) {
    int i = blockIdx.x * blockDim.x + threadIdx.x;   // pair index
    if (i >= NpairsPad) return;
    float v[2][8];
    for (int h = 0; h < 2; ++h) {
        int n = 2 * i + h;
        float a0=0.f,a1=0.f,a2=0.f,b0=0.f,b1=0.f,b2=0.f,c=0.f,w=0.f;
        if (n < N) {
            const float K = -0.7213475204444817f;  // -0.5 * log2(e)
            float q0 = positions[3*n+0], q1 = positions[3*n+1], q2 = positions[3*n+2];
            float iv0 = 1.0f / (__expf(2.0f*log_scales[3*n+0]) + 1e-6f);
            float iv1 = 1.0f / (__expf(2.0f*log_scales[3*n+1]) + 1e-6f);
            float iv2 = 1.0f / (__expf(2.0f*log_scales[3*n+2]) + 1e-6f);
            a0 = K * (-2.f*iv0*q0);  b0 = K * iv0;
            a1 = K * (-2.f*iv1*q1);  b1 = K * iv1;
            a2 = K * (-2.f*iv2*q2);  b2 = K * iv2;
            c  = K * (iv0*q0*q0 + iv1*q1*q1 + iv2*q2*q2);
            w  = intensities[n];
        }
        v[h][0]=a0; v[h][1]=a1; v[h][2]=a2; v[h][3]=b0;
        v[h][4]=b1; v[h][5]=b2; v[h][6]=c;  v[h][7]=w;
    }
    float4* out = (float4*)(coef + (size_t)i * 16);
    out[0] = make_float4(v[0][0], v[1][0], v[0][1], v[1][1]);  // a0.xy a1.xy
    out[1] = make_float4(v[0][2], v[1][2], v[0][3], v[1][3]);  // a2.xy b0.xy
    out[2] = make_float4(v[0][4], v[1][4], v[0][5], v[1][5]);  // b1.xy b2.xy
    out[3] = make_float4(v[0][6], v[1][6], v[0][7], v[1][7]);  // c.xy  w.xy
}

// --- main: 8 points/thread, wave sweeps a 16-pair (1 KB) gaussian slice ---
__global__ __launch_bounds__(BLOCK) void fgm_main(const float* __restrict__ points,
                                                  const float* __restrict__ coef,
                                                  float* __restrict__ out,
                                                  int M, int pairsPerSlice) {
    __shared__ float red[WAVES_PER_BLOCK][TILE_PTS];  // 8 KB

    int lane = threadIdx.x & 63;
    int wave = __builtin_amdgcn_readfirstlane(threadIdx.x >> 6);
    int tileBase = blockIdx.x * TILE_PTS;
    int slice = blockIdx.y * WAVES_PER_BLOCK + wave;

    float px[PTS_PER_LANE], py[PTS_PER_LANE], pz[PTS_PER_LANE];
    float qx[PTS_PER_LANE], qy[PTS_PER_LANE], qz[PTS_PER_LANE];
    v2f acc[PTS_PER_LANE];
    #pragma unroll
    for (int j = 0; j < PTS_PER_LANE; ++j) {
        int m = tileBase + lane + 64 * j;
        float x = 0.f, y = 0.f, z = 0.f;
        if (m < M) { x = points[3*m+0]; y = points[3*m+1]; z = points[3*m+2]; }
        px[j] = x;   py[j] = y;   pz[j] = z;
        qx[j] = x*x; qy[j] = y*y; qz[j] = z*z;
        acc[j] = (v2f){0.f, 0.f};
    }

    const v2f* cp = (const v2f*)coef + (size_t)slice * pairsPerSlice * 8;
    #pragma unroll 2
    for (int i = 0; i < pairsPerSlice; ++i) {
        v2f A0 = cp[0], A1 = cp[1], A2 = cp[2], B0 = cp[3];
        v2f B1 = cp[4], B2 = cp[5], C  = cp[6], W  = cp[7];
        cp += 8;
        #pragma unroll
        for (int j = 0; j < PTS_PER_LANE; ++j) {
            v2f t = __builtin_elementwise_fma(A0, (v2f){px[j], px[j]}, C);
            t = __builtin_elementwise_fma(A1, (v2f){py[j], py[j]}, t);
            t = __builtin_elementwise_fma(A2, (v2f){pz[j], pz[j]}, t);
            t = __builtin_elementwise_fma(B0, (v2f){qx[j], qx[j]}, t);
            t = __builtin_elementwise_fma(B1, (v2f){qy[j], qy[j]}, t);
            t = __builtin_elementwise_fma(B2, (v2f){qz[j], qz[j]}, t);
            v2f g;
            g.x = __builtin_amdgcn_exp2f(t.x);
            g.y = __builtin_amdgcn_exp2f(t.y);
            acc[j] = __builtin_elementwise_fma(g, W, acc[j]);
        }
    }

    #pragma unroll
    for (int j = 0; j < PTS_PER_LANE; ++j)
        red[wave][lane + 64 * j] = acc[j].x + acc[j].y;
    __syncthreads();

    for (int p = threadIdx.x; p < TILE_PTS; p += BLOCK) {
        int m = tileBase + p;
        if (m < M) {
            float s = (red[0][p] + red[1][p]) + (red[2][p] + red[3][p]);
            atomicAdd(&out[m], s);
        }
    }
}

extern "C" void kernel_launch(void* const* d_in, const int* in_sizes, int n_in,
                              void* d_out, int out_size, void* d_ws, size_t ws_size,
                              hipStream_t stream) {
    const float* points      = (const float*)d_in[0];
    const float* positions   = (const float*)d_in[1];
    const float* log_scales  = (const float*)d_in[2];
    const float* intensities = (const float*)d_in[3];
    int M = in_sizes[0] / 3;
    int N = in_sizes[3];

    int Npairs        = (N + 1) / 2;
    int pairsPerSlice = (Npairs + TOTAL_SLICES - 1) / TOTAL_SLICES;
    int NpairsPad     = pairsPerSlice * TOTAL_SLICES;  // prep zero-pads (w=0)

    float* coef = (float*)d_ws;  // NpairsPad * 16 floats

    // out accumulated via atomics -> zero it (d_out is poisoned 0xAA)
    hipMemsetAsync(d_out, 0, (size_t)out_size * sizeof(float), stream);

    fgm_prep<<<(NpairsPad + 255) / 256, 256, 0, stream>>>(positions, log_scales,
                                                          intensities, coef,
                                                          N, NpairsPad);

    int tiles = (M + TILE_PTS - 1) / TILE_PTS;   // 98
    dim3 grid(tiles, SLICE_GROUPS);
    fgm_main<<<grid, BLOCK, 0, stream>>>(points, coef, (float*)d_out,
                                         M, pairsPerSlice);
}

// Round 6
// 74.231 us; speedup vs baseline: 1.0521x; 1.0521x over previous
//
#include <hip/hip_runtime.h>

// FastGaussianModel: values[m] = sum_n exp(-0.5 * sum_d (p[m,d]-q[n,d])^2 * iv[n,d]) * w[n]
//
// Round 6: exp-bound model. All four prior feed structures landed ~17-19us
// -> VALU/transcendental-bound (v_exp_f32 ~1/8 wave rate ~16cyc; v2f fma =
// 2x v_fma_f32, no double-rate fp32). Levers:
//  (a) log_scales are constant across gaussians (detected at runtime, general
//      fallback kept): b.p^2 term is gaussian-independent -> fold into a
//      per-point seed pp = b.p^2; inner loop = 3 fma + 1 add + 1 acc fma
//      + exp per pair (was 6 fma + 1 acc). Seed inside exp arg: t<=0, safe.
//  (b) occupancy smoothing: 2-wave blocks, 4 pts/lane, 3136 blocks ~12.25/CU
//      all co-resident (6.1 waves/SIMD) to overlap the exp pipe.

typedef float v2f __attribute__((ext_vector_type(2)));

constexpr int BLOCK         = 128;                  // 2 waves
constexpr int WAVES_PER_BLK = 2;
constexpr int PTS_PER_LANE  = 4;
constexpr int TILE_PTS      = 64 * PTS_PER_LANE;    // 256 points per block
constexpr int SLICE_GROUPS  = 16;                   // grid.y
constexpr int TOTAL_SLICES  = SLICE_GROUPS * WAVES_PER_BLK;  // 32

// ws layout: [0..15] header (flag, b0, b1, b2, pad...), then pair records.
// record per pair i (16 floats): [a0.xy a1.xy | a2.xy b0.xy | b1.xy b2.xy | c.xy w.xy]

// --- prep: single block; packs records AND detects shared-scale fast path ---
__global__ void fgm_prep(const float* __restrict__ positions,
                         const float* __restrict__ log_scales,
                         const float* __restrict__ intensities,
                         float* __restrict__ ws, int N, int NpairsPad) {
    __shared__ int smismatch;
    if (threadIdx.x == 0) smismatch = 0;
    __syncthreads();

    const float K = -0.7213475204444817f;  // -0.5 * log2(e)
    // reference b (gaussian 0) — broadcast loads
    float r0 = K / (__expf(2.0f*log_scales[0]) + 1e-6f);
    float r1 = K / (__expf(2.0f*log_scales[1]) + 1e-6f);
    float r2 = K / (__expf(2.0f*log_scales[2]) + 1e-6f);

    int mism = 0;
    float* coef = ws + 16;
    for (int i = threadIdx.x; i < NpairsPad; i += blockDim.x) {
        float v[2][8];
        for (int h = 0; h < 2; ++h) {
            int n = 2*i + h;
            float a0=0.f,a1=0.f,a2=0.f,b0=0.f,b1=0.f,b2=0.f,c=0.f,w=0.f;
            if (n < N) {
                float q0 = positions[3*n+0], q1 = positions[3*n+1], q2 = positions[3*n+2];
                b0 = K / (__expf(2.0f*log_scales[3*n+0]) + 1e-6f);
                b1 = K / (__expf(2.0f*log_scales[3*n+1]) + 1e-6f);
                b2 = K / (__expf(2.0f*log_scales[3*n+2]) + 1e-6f);
                a0 = -2.f*b0*q0;  a1 = -2.f*b1*q1;  a2 = -2.f*b2*q2;
                c  = b0*q0*q0 + b1*q1*q1 + b2*q2*q2;
                w  = intensities[n];
                if (b0 != r0 || b1 != r1 || b2 != r2) mism = 1;
            }
            v[h][0]=a0; v[h][1]=a1; v[h][2]=a2; v[h][3]=b0;
            v[h][4]=b1; v[h][5]=b2; v[h][6]=c;  v[h][7]=w;
        }
        float4* out = (float4*)(coef + (size_t)i * 16);
        out[0] = make_float4(v[0][0], v[1][0], v[0][1], v[1][1]);
        out[1] = make_float4(v[0][2], v[1][2], v[0][3], v[1][3]);
        out[2] = make_float4(v[0][4], v[1][4], v[0][5], v[1][5]);
        out[3] = make_float4(v[0][6], v[1][6], v[0][7], v[1][7]);
    }
    if (mism) atomicOr(&smismatch, 1);
    __syncthreads();
    if (threadIdx.x == 0) {
        ws[0] = smismatch ? 1.f : 0.f;
        ws[1] = r0;  ws[2] = r1;  ws[3] = r2;
    }
}

template <bool FAST>
__device__ __forceinline__ void sweep(const v2f* __restrict__ cp, int pairs,
                                      const float* px, const float* py,
                                      const float* pz, const float* pp,
                                      v2f* acc) {
    #pragma unroll 2
    for (int i = 0; i < pairs; ++i) {
        v2f A0 = cp[0], A1 = cp[1], A2 = cp[2];
        v2f B0 = cp[3], B1 = cp[4], B2 = cp[5];
        v2f C  = cp[6], W  = cp[7];
        cp += 8;
        #pragma unroll
        for (int j = 0; j < PTS_PER_LANE; ++j) {
            v2f t;
            if (FAST) {
                t = C + (v2f){pp[j], pp[j]};          // b.p^2 folded per point
            } else {
                t = __builtin_elementwise_fma(B0, (v2f){px[j]*px[j], px[j]*px[j]},  C);
                t = __builtin_elementwise_fma(B1, (v2f){py[j]*py[j], py[j]*py[j]},  t);
                t = __builtin_elementwise_fma(B2, (v2f){pz[j]*pz[j], pz[j]*pz[j]},  t);
            }
            t = __builtin_elementwise_fma(A2, (v2f){pz[j], pz[j]}, t);
            t = __builtin_elementwise_fma(A1, (v2f){py[j], py[j]}, t);
            t = __builtin_elementwise_fma(A0, (v2f){px[j], px[j]}, t);
            v2f g;
            g.x = __builtin_amdgcn_exp2f(t.x);
            g.y = __builtin_amdgcn_exp2f(t.y);
            acc[j] = __builtin_elementwise_fma(g, W, acc[j]);
        }
    }
}

// --- main: 2 waves/block, 4 pts/lane, wave sweeps a 16-pair slice ---
__global__ __launch_bounds__(BLOCK) void fgm_main(const float* __restrict__ points,
                                                  const float* __restrict__ ws,
                                                  float* __restrict__ out,
                                                  int M, int pairsPerSlice) {
    __shared__ float red[WAVES_PER_BLK][TILE_PTS];  // 2 KB

    int lane = threadIdx.x & 63;
    int wave = __builtin_amdgcn_readfirstlane(threadIdx.x >> 6);
    int tileBase = blockIdx.x * TILE_PTS;
    int slice = blockIdx.y * WAVES_PER_BLK + wave;

    // header (uniform)
    bool fast = (ws[0] == 0.f);
    float hb0 = ws[1], hb1 = ws[2], hb2 = ws[3];

    float px[PTS_PER_LANE], py[PTS_PER_LANE], pz[PTS_PER_LANE], pp[PTS_PER_LANE];
    v2f acc[PTS_PER_LANE];
    #pragma unroll
    for (int j = 0; j < PTS_PER_LANE; ++j) {
        int m = tileBase + lane + 64*j;
        float x = 0.f, y = 0.f, z = 0.f;
        if (m < M) { x = points[3*m+0]; y = points[3*m+1]; z = points[3*m+2]; }
        px[j] = x;  py[j] = y;  pz[j] = z;
        pp[j] = hb0*x*x + hb1*y*y + hb2*z*z;   // <= 0
        acc[j] = (v2f){0.f, 0.f};
    }

    const v2f* cp = (const v2f*)(ws + 16) + (size_t)slice * pairsPerSlice * 8;
    if (fast) sweep<true >(cp, pairsPerSlice, px, py, pz, pp, acc);
    else      sweep<false>(cp, pairsPerSlice, px, py, pz, pp, acc);

    #pragma unroll
    for (int j = 0; j < PTS_PER_LANE; ++j)
        red[wave][lane + 64*j] = acc[j].x + acc[j].y;
    __syncthreads();

    for (int p = threadIdx.x; p < TILE_PTS; p += BLOCK) {
        int m = tileBase + p;
        if (m < M) atomicAdd(&out[m], red[0][p] + red[1][p]);
    }
}

extern "C" void kernel_launch(void* const* d_in, const int* in_sizes, int n_in,
                              void* d_out, int out_size, void* d_ws, size_t ws_size,
                              hipStream_t stream) {
    const float* points      = (const float*)d_in[0];
    const float* positions   = (const float*)d_in[1];
    const float* log_scales  = (const float*)d_in[2];
    const float* intensities = (const float*)d_in[3];
    int M = in_sizes[0] / 3;
    int N = in_sizes[3];

    int Npairs        = (N + 1) / 2;
    int pairsPerSlice = (Npairs + TOTAL_SLICES - 1) / TOTAL_SLICES;   // 16
    int NpairsPad     = pairsPerSlice * TOTAL_SLICES;                 // 512

    float* ws = (float*)d_ws;  // 16-float header + NpairsPad*16 floats

    // out accumulated via atomics -> zero it (d_out is poisoned 0xAA)
    hipMemsetAsync(d_out, 0, (size_t)out_size * sizeof(float), stream);

    fgm_prep<<<1, 256, 0, stream>>>(positions, log_scales, intensities,
                                    ws, N, NpairsPad);

    int tiles = (M + TILE_PTS - 1) / TILE_PTS;   // 196
    dim3 grid(tiles, SLICE_GROUPS);
    fgm_main<<<grid, BLOCK, 0, stream>>>(points, ws, (float*)d_out,
                                         M, pairsPerSlice);
}